// Round 13
// baseline (139.134 us; speedup 1.0000x reference)
//
#include <hip/hip_runtime.h>
#include <hip/hip_bf16.h>

constexpr int D        = 128;   // feature dim = K = UNITS
constexpr int BM       = 64;    // nodes per block in GEMM
constexpr int CHUNK    = 4096;  // edges per binning block
constexpr int NBKT_PAD = 1024;  // padded bucket count (actual = ceil(N/128) = 782)
constexpr int BKT_CAP  = 3072;  // sort_gather LDS capacity (mean 2048, sigma ~45)
constexpr int BKT_STRIDE = 4096; // fixed per-bucket region in bucketArr
constexpr int OVF_CAP  = 65536; // overflow list (never used statistically)
constexpr int EPT      = CHUNK / 256;  // edges per thread in bin role (16)

typedef __attribute__((ext_vector_type(8))) short bf16x8;
typedef __attribute__((ext_vector_type(4))) float f32x4;

__device__ __forceinline__ unsigned short rne_bf16(float f) {
    unsigned u = __float_as_uint(f);
    return (unsigned short)((u + 0x7FFF + ((u >> 16) & 1)) >> 16);
}

// ---------------------------------------------------------------------------
// One-time: W[k][f] f32 -> Wt (plain transposed [f][k] bf16). B-fragments are
// read from this directly (global, L1/L2-hot) -- no LDS stage, no swizzle.
// ---------------------------------------------------------------------------
__global__ __launch_bounds__(256) void transpose_W(
    const float* __restrict__ W, unsigned short* __restrict__ wt)
{
    int idx = blockIdx.x * 256 + threadIdx.x;   // 16384 elems
    int k = idx >> 7, f = idx & 127;
    wt[f * 128 + k] = rne_bf16(W[idx]);
}

// ---------------------------------------------------------------------------
// Fused kernel. Blocks [0, bin_blocks) bin edges into 128-row buckets
// (register-cached er, LDS cursors, direct global writes into dense bucket
// regions). Blocks [bin_blocks, ...) run the MFMA GEMM+gate (x -> h bf16)
// with B read from global. Bin-first ordering overlaps roles from dispatch 0.
// LDS: max(17.4KB gemm, 12.3KB bin) -> ~5 blocks/CU.
// ---------------------------------------------------------------------------
__global__ __launch_bounds__(256) void gemm_bin(
    const float* __restrict__ x, const unsigned short* __restrict__ wt,
    const float* __restrict__ Wg, const float* __restrict__ bg,
    __hip_bfloat16* __restrict__ h,
    const int* __restrict__ er, const int* __restrict__ ec,
    const float* __restrict__ ev, int* __restrict__ gcursor,
    uint2* __restrict__ bucketArr, int* __restrict__ ovfCur,
    uint4* __restrict__ ovfArr,
    int n_nodes, int n_edges, int bin_blocks)
{
    __shared__ __align__(16) char smem[17664];

    const int t    = threadIdx.x;
    const int lane = t & 63;
    const int w    = t >> 6;

    if ((int)blockIdx.x >= bin_blocks) {
        // =====================  GEMM + gate role  =====================
        unsigned short* Ahi  = (unsigned short*)smem;          // [64][128] swz, 16KB
        float*          Gs   = (float*)(smem + 17408);         // [64], 256B
        unsigned short* Cbuf = (unsigned short*)smem;          // [64][136] reuse, 17.4KB

        const int node0 = ((int)blockIdx.x - bin_blocks) * BM;

        // stage x tile as bf16, XOR-swizzled
        #pragma unroll
        for (int i = 0; i < 8; ++i) {
            int fidx = (i * 256 + t) * 4;
            int row  = fidx >> 7;
            int k    = fidx & 127;
            int node = node0 + row;
            float4 v = make_float4(0.f, 0.f, 0.f, 0.f);
            if (node < n_nodes) v = *(const float4*)(x + (size_t)node * D + k);
            unsigned long long pk =
                (unsigned long long)rne_bf16(v.x) |
                ((unsigned long long)rne_bf16(v.y) << 16) |
                ((unsigned long long)rne_bf16(v.z) << 32) |
                ((unsigned long long)rne_bf16(v.w) << 48);
            int eidx = row * 128 + (k ^ ((row & 7) << 3));
            *(unsigned long long*)&Ahi[eidx] = pk;
        }
        __syncthreads();

        // gate (threads 0..63)
        if (t < BM) {
            float gp = 0.f;
            #pragma unroll
            for (int kq = 0; kq < 16; ++kq) {
                int eidx = t * 128 + ((kq * 8) ^ ((t & 7) << 3));
                unsigned long long a = *(const unsigned long long*)&Ahi[eidx];
                unsigned long long b = *(const unsigned long long*)&Ahi[eidx + 4];
                #pragma unroll
                for (int j = 0; j < 4; ++j) {
                    gp += __uint_as_float((unsigned)((a >> (16 * j)) & 0xFFFF) << 16) * Wg[kq * 8 + j];
                    gp += __uint_as_float((unsigned)((b >> (16 * j)) & 0xFFFF) << 16) * Wg[kq * 8 + 4 + j];
                }
            }
            Gs[t] = 1.f / (1.f + __expf(-(gp + bg[0])));
        }

        // MFMA main loop (32 MFMAs); B-fragments straight from global wt
        f32x4 acc[4][2];
        #pragma unroll
        for (int m = 0; m < 4; ++m)
            #pragma unroll
            for (int n = 0; n < 2; ++n)
                acc[m][n] = (f32x4){0.f, 0.f, 0.f, 0.f};

        #pragma unroll
        for (int kk = 0; kk < 4; ++kk) {
            const int k0 = kk * 32 + (lane >> 4) * 8;
            bf16x8 bfr[2];
            #pragma unroll
            for (int n = 0; n < 2; ++n) {
                int f = w * 32 + n * 16 + (lane & 15);
                bfr[n] = *(const bf16x8*)&wt[f * 128 + k0];    // 16B aligned
            }
            #pragma unroll
            for (int m = 0; m < 4; ++m) {
                int row = m * 16 + (lane & 15);
                bf16x8 ah = *(const bf16x8*)&Ahi[row * 128 + (k0 ^ ((row & 7) << 3))];
                #pragma unroll
                for (int n = 0; n < 2; ++n)
                    acc[m][n] = __builtin_amdgcn_mfma_f32_16x16x32_bf16(ah, bfr[n], acc[m][n], 0, 0, 0);
            }
        }
        __syncthreads();   // Ahi dead; Gs ready

        // epilogue: gate-scale, cvt bf16, scatter to Cbuf [64][136]
        #pragma unroll
        for (int m = 0; m < 4; ++m) {
            #pragma unroll
            for (int n = 0; n < 2; ++n) {
                int feat = w * 32 + n * 16 + (lane & 15);
                #pragma unroll
                for (int j = 0; j < 4; ++j) {
                    int rloc = m * 16 + (lane >> 4) * 4 + j;
                    Cbuf[rloc * 136 + feat] = rne_bf16(acc[m][n][j] * Gs[rloc]);
                }
            }
        }
        __syncthreads();

        // coalesced store
        {
            int row  = t >> 2;
            int fb   = (t & 3) * 32;
            int node = node0 + row;
            if (node < n_nodes) {
                __hip_bfloat16* hp = h + (size_t)node * D + fb;
                #pragma unroll
                for (int q = 0; q < 4; ++q)
                    *(int4*)(hp + q * 8) = *(const int4*)&Cbuf[row * 136 + fb + q * 8];
            }
        }
    } else {
        // =====================  bin role  =====================
        int* lcnt  = (int*)smem;               // 4 KB
        int* lbase = lcnt + NBKT_PAD;          // 4 KB
        int* gbase = lbase + NBKT_PAD;         // 4 KB
        int* wt4   = gbase + NBKT_PAD;         // 16 B

        const int e0 = (int)blockIdx.x * CHUNK;
        const int ecnt = min(CHUNK, n_edges - e0);

        for (int i = t; i < NBKT_PAD; i += 256) lcnt[i] = 0;
        __syncthreads();

        // histogram, caching er in registers (single global read of er)
        int rcache[EPT];
        #pragma unroll
        for (int j = 0; j < EPT; ++j) {
            int i = t + j * 256;
            if (i < ecnt) {
                rcache[j] = er[e0 + i];
                atomicAdd(&lcnt[rcache[j] >> 7], 1);
            } else rcache[j] = -1;
        }
        __syncthreads();

        {   // exclusive scan of 1024 counters + global region reserve; lcnt -> cursor
            const int base = t * 4;
            int v[4], tsum = 0;
            #pragma unroll
            for (int j = 0; j < 4; ++j) { v[j] = lcnt[base + j]; tsum += v[j]; }
            int x2 = tsum;
            #pragma unroll
            for (int d = 1; d < 64; d <<= 1) {
                int y = __shfl_up(x2, d);
                if (lane >= d) x2 += y;
            }
            if (lane == 63) wt4[w] = x2;
            __syncthreads();
            int woff = 0;
            for (int i = 0; i < w; ++i) woff += wt4[i];
            int run = woff + x2 - tsum;
            #pragma unroll
            for (int j = 0; j < 4; ++j) {
                lbase[base + j] = run; run += v[j];
                if (v[j]) gbase[base + j] = atomicAdd(&gcursor[base + j], v[j]);
                lcnt[base + j] = 0;
            }
        }
        __syncthreads();

        // rank-assign via LDS cursors, write directly to global bucket regions
        #pragma unroll
        for (int j = 0; j < EPT; ++j) {
            int i = t + j * 256;
            if (rcache[j] >= 0) {
                int r = rcache[j];
                int b = r >> 7;
                int rank = atomicAdd(&lcnt[b], 1);
                int pos  = gbase[b] + rank;
                uint2 pe = make_uint2((unsigned)ec[e0 + i] | ((unsigned)(r & 127) << 17),
                                      (unsigned)__float_as_int(ev[e0 + i]));
                if (pos < BKT_STRIDE) {
                    bucketArr[(size_t)b * BKT_STRIDE + pos] = pe;
                } else {
                    int op = atomicAdd(ovfCur, 1);
                    if (op < OVF_CAP) ovfArr[op] = make_uint4((unsigned)b, pe.x, pe.y, 0u);
                }
            }
        }
    }
}

// ---------------------------------------------------------------------------
// Fused sort + gather (1 block per 128-row bucket). Segment read ONCE into
// registers (static-indexed, sentinel-padded); hist+scatter from registers.
// ---------------------------------------------------------------------------
__global__ __launch_bounds__(256) void sort_gather(
    const int* __restrict__ gcursor, const uint2* __restrict__ bucketArr,
    const int* __restrict__ ovfCur, const uint4* __restrict__ ovfArr,
    const __hip_bfloat16* __restrict__ h, float* __restrict__ out, int n_nodes)
{
    __shared__ uint2 sEdges[BKT_CAP];   // 24 KB
    __shared__ int rcnt[128];
    __shared__ int rbase[129];
    __shared__ int rfill[128];
    __shared__ int wt2[2];

    const int t = threadIdx.x, lane = t & 63, w = t >> 6;
    const int b = blockIdx.x;
    const int r0 = b << 7;
    const size_t s = (size_t)b * BKT_STRIDE;
    const int total = gcursor[b];
    const int cnt = min(total, BKT_STRIDE);
    const bool ovf = cnt > BKT_CAP;     // LDS-sort overflow: filtered-global path
    const int ovfN = (total > BKT_STRIDE || *ovfCur > 0) ? min(*ovfCur, OVF_CAP) : 0;

    if (t < 128) rcnt[t] = 0;
    __syncthreads();

    // read segment once into registers (BKT_CAP = 12*256)
    uint2 ecache[12];
    if (!ovf) {
        #pragma unroll
        for (int j = 0; j < 12; ++j) {
            int i = t + j * 256;
            ecache[j] = (i < cnt) ? bucketArr[s + i] : make_uint2(0xFFFFFFFFu, 0u);
        }
        #pragma unroll
        for (int j = 0; j < 12; ++j)
            if (ecache[j].x != 0xFFFFFFFFu)
                atomicAdd(&rcnt[(ecache[j].x >> 17) & 127], 1);
    }
    __syncthreads();

    // exclusive scan of 128 row counts (waves 0,1)
    {
        int v = 0, x = 0;
        if (t < 128) {
            v = rcnt[t];
            x = v;
            #pragma unroll
            for (int d = 1; d < 64; d <<= 1) {
                int y = __shfl_up(x, d);
                if (lane >= d) x += y;
            }
            if (lane == 63) wt2[w] = x;
        }
        __syncthreads();
        if (t < 128) {
            int rb = (w ? wt2[0] : 0) + x - v;
            rbase[t] = rb;
            rfill[t] = rb;
        }
        if (t == 0) rbase[128] = cnt;
    }
    __syncthreads();

    if (!ovf) {
        #pragma unroll
        for (int j = 0; j < 12; ++j) {
            if (ecache[j].x != 0xFFFFFFFFu) {
                int rl = (ecache[j].x >> 17) & 127;
                int p  = atomicAdd(&rfill[rl], 1);
                sEdges[p] = ecache[j];
            }
        }
    }
    __syncthreads();

    // ---- gather phase: wave w -> rows rl = w + 4k
    const int g = lane >> 4;            // edge slot group 0..3
    const int p = lane & 15;            // feat block (8 feats)

    for (int k = 0; k < 32; ++k) {
        const int rl = w + (k << 2);
        const int row = r0 + rl;
        if (row >= n_nodes) continue;

        float acc[8];
        #pragma unroll
        for (int j = 0; j < 8; ++j) acc[j] = 0.f;

        if (!ovf) {
            const int rs = rbase[rl], re = rbase[rl + 1];
            for (int bb = rs; bb < re; bb += 8) {
                int i0 = bb + g;
                int i1 = i0 + 4;
                float v0 = 0.f, v1 = 0.f;
                int c0 = 0, c1 = 0;
                if (i0 < re) { uint2 pk = sEdges[i0]; v0 = __uint_as_float(pk.y); c0 = (int)(pk.x & 0x1FFFFu); }
                if (i1 < re) { uint2 pk = sEdges[i1]; v1 = __uint_as_float(pk.y); c1 = (int)(pk.x & 0x1FFFFu); }
                const int4 h0 = *(const int4*)(h + (size_t)c0 * D + p * 8);
                const int4 h1 = *(const int4*)(h + (size_t)c1 * D + p * 8);
                {
                    unsigned d0 = (unsigned)h0.x, d1 = (unsigned)h0.y, d2 = (unsigned)h0.z, d3 = (unsigned)h0.w;
                    acc[0] += v0 * __uint_as_float(d0 << 16);
                    acc[1] += v0 * __uint_as_float(d0 & 0xFFFF0000u);
                    acc[2] += v0 * __uint_as_float(d1 << 16);
                    acc[3] += v0 * __uint_as_float(d1 & 0xFFFF0000u);
                    acc[4] += v0 * __uint_as_float(d2 << 16);
                    acc[5] += v0 * __uint_as_float(d2 & 0xFFFF0000u);
                    acc[6] += v0 * __uint_as_float(d3 << 16);
                    acc[7] += v0 * __uint_as_float(d3 & 0xFFFF0000u);
                }
                {
                    unsigned d0 = (unsigned)h1.x, d1 = (unsigned)h1.y, d2 = (unsigned)h1.z, d3 = (unsigned)h1.w;
                    acc[0] += v1 * __uint_as_float(d0 << 16);
                    acc[1] += v1 * __uint_as_float(d0 & 0xFFFF0000u);
                    acc[2] += v1 * __uint_as_float(d1 << 16);
                    acc[3] += v1 * __uint_as_float(d1 & 0xFFFF0000u);
                    acc[4] += v1 * __uint_as_float(d2 << 16);
                    acc[5] += v1 * __uint_as_float(d2 & 0xFFFF0000u);
                    acc[6] += v1 * __uint_as_float(d3 << 16);
                    acc[7] += v1 * __uint_as_float(d3 & 0xFFFF0000u);
                }
            }
        } else {
            // filtered scan of the whole (unsorted) global segment
            const unsigned target = (unsigned)rl;
            for (int bb = 0; bb < cnt; bb += 8) {
                int i0 = bb + g;
                int i1 = i0 + 4;
                float v0 = 0.f, v1 = 0.f;
                int c0 = 0, c1 = 0;
                if (i0 < cnt) {
                    uint2 pk = bucketArr[s + i0];
                    if (((pk.x >> 17) & 127u) == target) { v0 = __uint_as_float(pk.y); c0 = (int)(pk.x & 0x1FFFFu); }
                }
                if (i1 < cnt) {
                    uint2 pk = bucketArr[s + i1];
                    if (((pk.x >> 17) & 127u) == target) { v1 = __uint_as_float(pk.y); c1 = (int)(pk.x & 0x1FFFFu); }
                }
                const int4 h0 = *(const int4*)(h + (size_t)c0 * D + p * 8);
                const int4 h1 = *(const int4*)(h + (size_t)c1 * D + p * 8);
                {
                    unsigned d0 = (unsigned)h0.x, d1 = (unsigned)h0.y, d2 = (unsigned)h0.z, d3 = (unsigned)h0.w;
                    acc[0] += v0 * __uint_as_float(d0 << 16);
                    acc[1] += v0 * __uint_as_float(d0 & 0xFFFF0000u);
                    acc[2] += v0 * __uint_as_float(d1 << 16);
                    acc[3] += v0 * __uint_as_float(d1 & 0xFFFF0000u);
                    acc[4] += v0 * __uint_as_float(d2 << 16);
                    acc[5] += v0 * __uint_as_float(d2 & 0xFFFF0000u);
                    acc[6] += v0 * __uint_as_float(d3 << 16);
                    acc[7] += v0 * __uint_as_float(d3 & 0xFFFF0000u);
                }
                {
                    unsigned d0 = (unsigned)h1.x, d1 = (unsigned)h1.y, d2 = (unsigned)h1.z, d3 = (unsigned)h1.w;
                    acc[0] += v1 * __uint_as_float(d0 << 16);
                    acc[1] += v1 * __uint_as_float(d0 & 0xFFFF0000u);
                    acc[2] += v1 * __uint_as_float(d1 << 16);
                    acc[3] += v1 * __uint_as_float(d1 & 0xFFFF0000u);
                    acc[4] += v1 * __uint_as_float(d2 << 16);
                    acc[5] += v1 * __uint_as_float(d2 & 0xFFFF0000u);
                    acc[6] += v1 * __uint_as_float(d3 << 16);
                    acc[7] += v1 * __uint_as_float(d3 & 0xFFFF0000u);
                }
            }
        }

        // overflow-list stragglers (rare path; group 0 only so reduce stays correct)
        if (ovfN > 0 && g == 0) {
            for (int j = 0; j < ovfN; ++j) {
                uint4 oe = ovfArr[j];
                if (oe.x == (unsigned)b && ((oe.y >> 17) & 127u) == (unsigned)rl) {
                    float v = __uint_as_float(oe.z);
                    int col = (int)(oe.y & 0x1FFFFu);
                    const int4 hv = *(const int4*)(h + (size_t)col * D + p * 8);
                    unsigned d0 = (unsigned)hv.x, d1 = (unsigned)hv.y, d2 = (unsigned)hv.z, d3 = (unsigned)hv.w;
                    acc[0] += v * __uint_as_float(d0 << 16);
                    acc[1] += v * __uint_as_float(d0 & 0xFFFF0000u);
                    acc[2] += v * __uint_as_float(d1 << 16);
                    acc[3] += v * __uint_as_float(d1 & 0xFFFF0000u);
                    acc[4] += v * __uint_as_float(d2 << 16);
                    acc[5] += v * __uint_as_float(d2 & 0xFFFF0000u);
                    acc[6] += v * __uint_as_float(d3 << 16);
                    acc[7] += v * __uint_as_float(d3 & 0xFFFF0000u);
                }
            }
        }

        // reduce across the 4 edge groups (lane bits 4,5)
        #pragma unroll
        for (int j = 0; j < 8; ++j) {
            acc[j] += __shfl_xor(acc[j], 16);
            acc[j] += __shfl_xor(acc[j], 32);
        }

        if (lane < 16) {
            float* op = out + (size_t)row * D + lane * 8;
            *(float4*)(op)     = make_float4(acc[0], acc[1], acc[2], acc[3]);
            *(float4*)(op + 4) = make_float4(acc[4], acc[5], acc[6], acc[7]);
        }
    }
}

// ---------------------------------------------------------------------------
// Fallback (ws too small): atomic scatter
// ---------------------------------------------------------------------------
__global__ __launch_bounds__(256) void scatter_edges(
    const int* __restrict__ er, const int* __restrict__ ec,
    const float* __restrict__ ev, const __hip_bfloat16* __restrict__ h,
    float* __restrict__ out, int n_edges)
{
    int gw   = (blockIdx.x * 256 + threadIdx.x) >> 6;
    int lane = threadIdx.x & 63;
    if (gw >= n_edges) return;
    int r = er[gw];
    int c = ec[gw];
    float v = ev[gw];
    unsigned hv = *(const unsigned*)(h + (size_t)c * D + lane * 2);
    float* op = out + (size_t)r * D + lane * 2;
    atomicAdd(op,     v * __uint_as_float(hv << 16));
    atomicAdd(op + 1, v * __uint_as_float(hv & 0xFFFF0000u));
}

extern "C" void kernel_launch(void* const* d_in, const int* in_sizes, int n_in,
                              void* d_out, int out_size, void* d_ws, size_t ws_size,
                              hipStream_t stream) {
    const float* x  = (const float*)d_in[0];
    const int*   er = (const int*)d_in[1];
    const int*   ec = (const int*)d_in[2];
    const float* ev = (const float*)d_in[3];
    const float* W  = (const float*)d_in[4];
    const float* Wg = (const float*)d_in[5];
    const float* bg = (const float*)d_in[6];
    float* out = (float*)d_out;

    const int n_nodes = in_sizes[0] / D;
    const int n_edges = in_sizes[1];
    const int nbkt = (n_nodes + 127) >> 7;   // 128-row buckets
    const int gemm_blocks = (n_nodes + BM - 1) / BM;
    const int bin_blocks  = (n_edges + CHUNK - 1) / CHUNK;

    char* ws = (char*)d_ws;
    size_t off = 0;
    auto alloc = [&](size_t bytes) {
        char* p = ws + off;
        off += (bytes + 15) & ~size_t(15);
        return p;
    };
    __hip_bfloat16* h = (__hip_bfloat16*)alloc((size_t)n_nodes * D * sizeof(__hip_bfloat16));
    unsigned short* wt = (unsigned short*)alloc((size_t)D * D * sizeof(unsigned short));
    uint2* bucketArr = (uint2*)alloc((size_t)nbkt * BKT_STRIDE * sizeof(uint2));
    int*   gcursor   = (int*)  alloc(NBKT_PAD * sizeof(int));   // | contiguous
    int*   ovfCur    = (int*)  alloc(16);                       // | memset
    uint4* ovfArr    = (uint4*)alloc((size_t)OVF_CAP * sizeof(uint4));
    bool have_ws = off <= ws_size;

    // W -> transposed bf16 (read directly by GEMM role)
    transpose_W<<<D * D / 256, 256, 0, stream>>>(W, wt);

    if (have_ws) {
        hipMemsetAsync(gcursor, 0, NBKT_PAD * sizeof(int) + 16, stream);  // gcursor+ovfCur
        // fused bin (first) + GEMM: co-scheduled from dispatch 0
        gemm_bin<<<bin_blocks + gemm_blocks, 256, 0, stream>>>(
            x, wt, Wg, bg, h, er, ec, ev, gcursor, bucketArr, ovfCur, ovfArr,
            n_nodes, n_edges, bin_blocks);
        sort_gather<<<nbkt, 256, 0, stream>>>(gcursor, bucketArr, ovfCur, ovfArr, h, out, n_nodes);
    } else {
        // fallback: gemm only (bin_blocks = 0), then atomic scatter
        gemm_bin<<<gemm_blocks, 256, 0, stream>>>(
            x, wt, Wg, bg, h, er, ec, ev, (int*)nullptr, (uint2*)nullptr,
            (int*)nullptr, (uint4*)nullptr, n_nodes, n_edges, 0);
        hipMemsetAsync(d_out, 0, (size_t)out_size * sizeof(float), stream);
        int blocks = (n_edges + 3) / 4;
        scatter_edges<<<blocks, 256, 0, stream>>>(er, ec, ev, h, out, n_edges);
    }
}

// Round 14
// 117.667 us; speedup vs baseline: 1.1824x; 1.1824x over previous
//
#include <hip/hip_runtime.h>
#include <hip/hip_bf16.h>

constexpr int D        = 128;   // feature dim = K = UNITS
constexpr int BM       = 64;    // nodes per block in GEMM
constexpr int CHUNK    = 4096;  // edges per binning block
constexpr int NBKT_PAD = 1024;  // padded bucket count (actual = ceil(N/128) = 782)
constexpr int BKT_CAP  = 3072;  // sort_gather LDS capacity (mean 2048, sigma ~45)
constexpr int BKT_STRIDE = 4096; // fixed per-bucket region in bucketArr
constexpr int OVF_CAP  = 65536; // overflow list (never used statistically)
constexpr int EPT      = CHUNK / 256;  // edges per thread in bin role (16)

typedef __attribute__((ext_vector_type(8))) short bf16x8;
typedef __attribute__((ext_vector_type(4))) float f32x4;

__device__ __forceinline__ unsigned short rne_bf16(float f) {
    unsigned u = __float_as_uint(f);
    return (unsigned short)((u + 0x7FFF + ((u >> 16) & 1)) >> 16);
}

// ---------------------------------------------------------------------------
// One-time: W[k][f] f32 -> Wt_sw (transposed [f][k] bf16, XOR-pre-swizzled)
// ---------------------------------------------------------------------------
__global__ __launch_bounds__(256) void transpose_W(
    const float* __restrict__ W, unsigned short* __restrict__ wt_sw)
{
    int idx = blockIdx.x * 256 + threadIdx.x;   // 16384 elems
    int k = idx >> 7, f = idx & 127;
    wt_sw[f * 128 + (k ^ ((f & 7) << 3))] = rne_bf16(W[idx]);
}

// ---------------------------------------------------------------------------
// Fused kernel. Blocks [0, bin_blocks) = LDS-staged edge binning (coalesced
// bucket-run writes). Blocks [bin_blocks, ...) = MFMA GEMM+gate (x -> h bf16).
// Bin-first ordering overlaps the roles from dispatch 0.
// ---------------------------------------------------------------------------
__global__ __launch_bounds__(256) void gemm_bin(
    const float* __restrict__ x, const unsigned short* __restrict__ wt_sw,
    const float* __restrict__ Wg, const float* __restrict__ bg,
    __hip_bfloat16* __restrict__ h,
    const int* __restrict__ er, const int* __restrict__ ec,
    const float* __restrict__ ev, int* __restrict__ gcursor,
    uint2* __restrict__ bucketArr, int* __restrict__ ovfCur,
    uint4* __restrict__ ovfArr,
    int n_nodes, int n_edges, int bin_blocks)
{
    __shared__ __align__(16) char smem[53264];   // union of roles, 3 blocks/CU

    const int t    = threadIdx.x;
    const int lane = t & 63;
    const int w    = t >> 6;

    if ((int)blockIdx.x >= bin_blocks) {
        // =====================  GEMM + gate role  =====================
        unsigned short* Ahi = (unsigned short*)smem;           // [64][128] swz, 16KB
        unsigned short* Bt  = Ahi + 64 * 128;                  // [128][128] swz, 32KB
        float*          Gs  = (float*)(Bt + 128 * 128);        // [64], 256B
        unsigned short* Cbuf = (unsigned short*)smem;          // [64][136] reuse

        const int node0 = ((int)blockIdx.x - bin_blocks) * BM;

        // stage W tile: linear copy of pre-swizzled source (conflict-free)
        #pragma unroll
        for (int i = 0; i < 8; ++i) {
            int e0 = (i * 256 + t) * 8;
            *(int4*)&Bt[e0] = *(const int4*)&wt_sw[e0];
        }

        // stage x tile as bf16, XOR-swizzled
        #pragma unroll
        for (int i = 0; i < 8; ++i) {
            int fidx = (i * 256 + t) * 4;
            int row  = fidx >> 7;
            int k    = fidx & 127;
            int node = node0 + row;
            float4 v = make_float4(0.f, 0.f, 0.f, 0.f);
            if (node < n_nodes) v = *(const float4*)(x + (size_t)node * D + k);
            unsigned long long pk =
                (unsigned long long)rne_bf16(v.x) |
                ((unsigned long long)rne_bf16(v.y) << 16) |
                ((unsigned long long)rne_bf16(v.z) << 32) |
                ((unsigned long long)rne_bf16(v.w) << 48);
            int eidx = row * 128 + (k ^ ((row & 7) << 3));
            *(unsigned long long*)&Ahi[eidx] = pk;
        }
        __syncthreads();

        // gate (threads 0..63)
        if (t < BM) {
            float gp = 0.f;
            #pragma unroll
            for (int kq = 0; kq < 16; ++kq) {
                int eidx = t * 128 + ((kq * 8) ^ ((t & 7) << 3));
                unsigned long long a = *(const unsigned long long*)&Ahi[eidx];
                unsigned long long b = *(const unsigned long long*)&Ahi[eidx + 4];
                #pragma unroll
                for (int j = 0; j < 4; ++j) {
                    gp += __uint_as_float((unsigned)((a >> (16 * j)) & 0xFFFF) << 16) * Wg[kq * 8 + j];
                    gp += __uint_as_float((unsigned)((b >> (16 * j)) & 0xFFFF) << 16) * Wg[kq * 8 + 4 + j];
                }
            }
            Gs[t] = 1.f / (1.f + __expf(-(gp + bg[0])));
        }

        // MFMA main loop (32 MFMAs)
        f32x4 acc[4][2];
        #pragma unroll
        for (int m = 0; m < 4; ++m)
            #pragma unroll
            for (int n = 0; n < 2; ++n)
                acc[m][n] = (f32x4){0.f, 0.f, 0.f, 0.f};

        #pragma unroll
        for (int kk = 0; kk < 4; ++kk) {
            const int k0 = kk * 32 + (lane >> 4) * 8;
            bf16x8 bfr[2];
            #pragma unroll
            for (int n = 0; n < 2; ++n) {
                int f = w * 32 + n * 16 + (lane & 15);
                bfr[n] = *(const bf16x8*)&Bt[f * 128 + (k0 ^ ((f & 7) << 3))];
            }
            #pragma unroll
            for (int m = 0; m < 4; ++m) {
                int row = m * 16 + (lane & 15);
                bf16x8 ah = *(const bf16x8*)&Ahi[row * 128 + (k0 ^ ((row & 7) << 3))];
                #pragma unroll
                for (int n = 0; n < 2; ++n)
                    acc[m][n] = __builtin_amdgcn_mfma_f32_16x16x32_bf16(ah, bfr[n], acc[m][n], 0, 0, 0);
            }
        }
        __syncthreads();   // A/B LDS dead; Gs ready

        // epilogue: gate-scale, cvt bf16, scatter to Cbuf [64][136]
        #pragma unroll
        for (int m = 0; m < 4; ++m) {
            #pragma unroll
            for (int n = 0; n < 2; ++n) {
                int feat = w * 32 + n * 16 + (lane & 15);
                #pragma unroll
                for (int j = 0; j < 4; ++j) {
                    int rloc = m * 16 + (lane >> 4) * 4 + j;
                    Cbuf[rloc * 136 + feat] = rne_bf16(acc[m][n][j] * Gs[rloc]);
                }
            }
        }
        __syncthreads();

        // coalesced store
        {
            int row  = t >> 2;
            int fb   = (t & 3) * 32;
            int node = node0 + row;
            if (node < n_nodes) {
                __hip_bfloat16* hp = h + (size_t)node * D + fb;
                #pragma unroll
                for (int q = 0; q < 4; ++q)
                    *(int4*)(hp + q * 8) = *(const int4*)&Cbuf[row * 136 + fb + q * 8];
            }
        }
    } else {
        // =====================  bin role (LDS-staged)  =====================
        uint2* staged           = (uint2*)smem;                       // 32 KB
        unsigned short* bkt_of  = (unsigned short*)(smem + 32768);    // 8 KB
        int* lcnt               = (int*)(smem + 40960);               // 4 KB
        int* lbase              = lcnt + NBKT_PAD;                    // 4 KB
        int* gbase              = lbase + NBKT_PAD;                   // 4 KB
        int* wt                 = gbase + NBKT_PAD;                   // 16 B

        const int e0 = (int)blockIdx.x * CHUNK;
        const int ecnt = min(CHUNK, n_edges - e0);

        for (int i = t; i < NBKT_PAD; i += 256) lcnt[i] = 0;
        __syncthreads();

        // histogram, caching er in registers (single global read of er)
        int rcache[EPT];
        #pragma unroll
        for (int j = 0; j < EPT; ++j) {
            int i = t + j * 256;
            if (i < ecnt) {
                rcache[j] = er[e0 + i];
                atomicAdd(&lcnt[rcache[j] >> 7], 1);
            } else rcache[j] = -1;
        }
        __syncthreads();

        {   // exclusive scan of 1024 counters; reset lcnt as cursor
            const int base = t * 4;
            int v[4], tsum = 0;
            #pragma unroll
            for (int j = 0; j < 4; ++j) { v[j] = lcnt[base + j]; tsum += v[j]; }
            int x2 = tsum;
            #pragma unroll
            for (int d = 1; d < 64; d <<= 1) {
                int y = __shfl_up(x2, d);
                if (lane >= d) x2 += y;
            }
            if (lane == 63) wt[w] = x2;
            __syncthreads();
            int woff = 0;
            for (int i = 0; i < w; ++i) woff += wt[i];
            int run = woff + x2 - tsum;
            #pragma unroll
            for (int j = 0; j < 4; ++j) { lbase[base + j] = run; run += v[j]; lcnt[base + j] = 0; }
        }
        __syncthreads();

        // scatter into LDS, bucket-grouped
        #pragma unroll
        for (int j = 0; j < EPT; ++j) {
            int i = t + j * 256;
            if (rcache[j] >= 0) {
                int r = rcache[j];
                int b = r >> 7;
                int p = lbase[b] + atomicAdd(&lcnt[b], 1);
                staged[p] = make_uint2((unsigned)ec[e0 + i] | ((unsigned)(r & 127) << 17),
                                       (unsigned)__float_as_int(ev[e0 + i]));
                bkt_of[p] = (unsigned short)b;
            }
        }
        __syncthreads();

        // reserve global space per bucket (fixed-stride regions)
        for (int i = t; i < NBKT_PAD; i += 256) {
            int c = lcnt[i];
            if (c) gbase[i] = atomicAdd(&gcursor[i], c);
        }
        __syncthreads();

        // bulk copy: contiguous LDS runs -> per-bucket global regions
        for (int i = t; i < ecnt; i += 256) {
            int b = bkt_of[i];
            int pos = gbase[b] + (i - lbase[b]);
            uint2 pe = staged[i];
            if (pos < BKT_STRIDE) {
                bucketArr[(size_t)b * BKT_STRIDE + pos] = pe;
            } else {
                int op = atomicAdd(ovfCur, 1);
                if (op < OVF_CAP) ovfArr[op] = make_uint4((unsigned)b, pe.x, pe.y, 0u);
            }
        }
    }
}

// ---------------------------------------------------------------------------
// Fused sort + gather (1 block per 128-row bucket). Segment read ONCE into
// registers (static-indexed, sentinel-padded); hist+scatter from registers.
// ---------------------------------------------------------------------------
__global__ __launch_bounds__(256) void sort_gather(
    const int* __restrict__ gcursor, const uint2* __restrict__ bucketArr,
    const int* __restrict__ ovfCur, const uint4* __restrict__ ovfArr,
    const __hip_bfloat16* __restrict__ h, float* __restrict__ out, int n_nodes)
{
    __shared__ uint2 sEdges[BKT_CAP];   // 24 KB
    __shared__ int rcnt[128];
    __shared__ int rbase[129];
    __shared__ int rfill[128];
    __shared__ int wt2[2];

    const int t = threadIdx.x, lane = t & 63, w = t >> 6;
    const int b = blockIdx.x;
    const int r0 = b << 7;
    const size_t s = (size_t)b * BKT_STRIDE;
    const int total = gcursor[b];
    const int cnt = min(total, BKT_STRIDE);
    const bool ovf = cnt > BKT_CAP;     // LDS-sort overflow: filtered-global path
    const int ovfN = (total > BKT_STRIDE || *ovfCur > 0) ? min(*ovfCur, OVF_CAP) : 0;

    if (t < 128) rcnt[t] = 0;
    __syncthreads();

    // read segment once into registers (BKT_CAP = 12*256)
    uint2 ecache[12];
    if (!ovf) {
        #pragma unroll
        for (int j = 0; j < 12; ++j) {
            int i = t + j * 256;
            ecache[j] = (i < cnt) ? bucketArr[s + i] : make_uint2(0xFFFFFFFFu, 0u);
        }
        #pragma unroll
        for (int j = 0; j < 12; ++j)
            if (ecache[j].x != 0xFFFFFFFFu)
                atomicAdd(&rcnt[(ecache[j].x >> 17) & 127], 1);
    }
    __syncthreads();

    // exclusive scan of 128 row counts (waves 0,1)
    {
        int v = 0, x = 0;
        if (t < 128) {
            v = rcnt[t];
            x = v;
            #pragma unroll
            for (int d = 1; d < 64; d <<= 1) {
                int y = __shfl_up(x, d);
                if (lane >= d) x += y;
            }
            if (lane == 63) wt2[w] = x;
        }
        __syncthreads();
        if (t < 128) {
            int rb = (w ? wt2[0] : 0) + x - v;
            rbase[t] = rb;
            rfill[t] = rb;
        }
        if (t == 0) rbase[128] = cnt;
    }
    __syncthreads();

    if (!ovf) {
        #pragma unroll
        for (int j = 0; j < 12; ++j) {
            if (ecache[j].x != 0xFFFFFFFFu) {
                int rl = (ecache[j].x >> 17) & 127;
                int p  = atomicAdd(&rfill[rl], 1);
                sEdges[p] = ecache[j];
            }
        }
    }
    __syncthreads();

    // ---- gather phase: wave w -> rows rl = w + 4k
    const int g = lane >> 4;            // edge slot group 0..3
    const int p = lane & 15;            // feat block (8 feats)

    for (int k = 0; k < 32; ++k) {
        const int rl = w + (k << 2);
        const int row = r0 + rl;
        if (row >= n_nodes) continue;

        float acc[8];
        #pragma unroll
        for (int j = 0; j < 8; ++j) acc[j] = 0.f;

        if (!ovf) {
            const int rs = rbase[rl], re = rbase[rl + 1];
            for (int bb = rs; bb < re; bb += 8) {
                int i0 = bb + g;
                int i1 = i0 + 4;
                float v0 = 0.f, v1 = 0.f;
                int c0 = 0, c1 = 0;
                if (i0 < re) { uint2 pk = sEdges[i0]; v0 = __uint_as_float(pk.y); c0 = (int)(pk.x & 0x1FFFFu); }
                if (i1 < re) { uint2 pk = sEdges[i1]; v1 = __uint_as_float(pk.y); c1 = (int)(pk.x & 0x1FFFFu); }
                const int4 h0 = *(const int4*)(h + (size_t)c0 * D + p * 8);
                const int4 h1 = *(const int4*)(h + (size_t)c1 * D + p * 8);
                {
                    unsigned d0 = (unsigned)h0.x, d1 = (unsigned)h0.y, d2 = (unsigned)h0.z, d3 = (unsigned)h0.w;
                    acc[0] += v0 * __uint_as_float(d0 << 16);
                    acc[1] += v0 * __uint_as_float(d0 & 0xFFFF0000u);
                    acc[2] += v0 * __uint_as_float(d1 << 16);
                    acc[3] += v0 * __uint_as_float(d1 & 0xFFFF0000u);
                    acc[4] += v0 * __uint_as_float(d2 << 16);
                    acc[5] += v0 * __uint_as_float(d2 & 0xFFFF0000u);
                    acc[6] += v0 * __uint_as_float(d3 << 16);
                    acc[7] += v0 * __uint_as_float(d3 & 0xFFFF0000u);
                }
                {
                    unsigned d0 = (unsigned)h1.x, d1 = (unsigned)h1.y, d2 = (unsigned)h1.z, d3 = (unsigned)h1.w;
                    acc[0] += v1 * __uint_as_float(d0 << 16);
                    acc[1] += v1 * __uint_as_float(d0 & 0xFFFF0000u);
                    acc[2] += v1 * __uint_as_float(d1 << 16);
                    acc[3] += v1 * __uint_as_float(d1 & 0xFFFF0000u);
                    acc[4] += v1 * __uint_as_float(d2 << 16);
                    acc[5] += v1 * __uint_as_float(d2 & 0xFFFF0000u);
                    acc[6] += v1 * __uint_as_float(d3 << 16);
                    acc[7] += v1 * __uint_as_float(d3 & 0xFFFF0000u);
                }
            }
        } else {
            // filtered scan of the whole (unsorted) global segment
            const unsigned target = (unsigned)rl;
            for (int bb = 0; bb < cnt; bb += 8) {
                int i0 = bb + g;
                int i1 = i0 + 4;
                float v0 = 0.f, v1 = 0.f;
                int c0 = 0, c1 = 0;
                if (i0 < cnt) {
                    uint2 pk = bucketArr[s + i0];
                    if (((pk.x >> 17) & 127u) == target) { v0 = __uint_as_float(pk.y); c0 = (int)(pk.x & 0x1FFFFu); }
                }
                if (i1 < cnt) {
                    uint2 pk = bucketArr[s + i1];
                    if (((pk.x >> 17) & 127u) == target) { v1 = __uint_as_float(pk.y); c1 = (int)(pk.x & 0x1FFFFu); }
                }
                const int4 h0 = *(const int4*)(h + (size_t)c0 * D + p * 8);
                const int4 h1 = *(const int4*)(h + (size_t)c1 * D + p * 8);
                {
                    unsigned d0 = (unsigned)h0.x, d1 = (unsigned)h0.y, d2 = (unsigned)h0.z, d3 = (unsigned)h0.w;
                    acc[0] += v0 * __uint_as_float(d0 << 16);
                    acc[1] += v0 * __uint_as_float(d0 & 0xFFFF0000u);
                    acc[2] += v0 * __uint_as_float(d1 << 16);
                    acc[3] += v0 * __uint_as_float(d1 & 0xFFFF0000u);
                    acc[4] += v0 * __uint_as_float(d2 << 16);
                    acc[5] += v0 * __uint_as_float(d2 & 0xFFFF0000u);
                    acc[6] += v0 * __uint_as_float(d3 << 16);
                    acc[7] += v0 * __uint_as_float(d3 & 0xFFFF0000u);
                }
                {
                    unsigned d0 = (unsigned)h1.x, d1 = (unsigned)h1.y, d2 = (unsigned)h1.z, d3 = (unsigned)h1.w;
                    acc[0] += v1 * __uint_as_float(d0 << 16);
                    acc[1] += v1 * __uint_as_float(d0 & 0xFFFF0000u);
                    acc[2] += v1 * __uint_as_float(d1 << 16);
                    acc[3] += v1 * __uint_as_float(d1 & 0xFFFF0000u);
                    acc[4] += v1 * __uint_as_float(d2 << 16);
                    acc[5] += v1 * __uint_as_float(d2 & 0xFFFF0000u);
                    acc[6] += v1 * __uint_as_float(d3 << 16);
                    acc[7] += v1 * __uint_as_float(d3 & 0xFFFF0000u);
                }
            }
        }

        // overflow-list stragglers (rare path; group 0 only so reduce stays correct)
        if (ovfN > 0 && g == 0) {
            for (int j = 0; j < ovfN; ++j) {
                uint4 oe = ovfArr[j];
                if (oe.x == (unsigned)b && ((oe.y >> 17) & 127u) == (unsigned)rl) {
                    float v = __uint_as_float(oe.z);
                    int col = (int)(oe.y & 0x1FFFFu);
                    const int4 hv = *(const int4*)(h + (size_t)col * D + p * 8);
                    unsigned d0 = (unsigned)hv.x, d1 = (unsigned)hv.y, d2 = (unsigned)hv.z, d3 = (unsigned)hv.w;
                    acc[0] += v * __uint_as_float(d0 << 16);
                    acc[1] += v * __uint_as_float(d0 & 0xFFFF0000u);
                    acc[2] += v * __uint_as_float(d1 << 16);
                    acc[3] += v * __uint_as_float(d1 & 0xFFFF0000u);
                    acc[4] += v * __uint_as_float(d2 << 16);
                    acc[5] += v * __uint_as_float(d2 & 0xFFFF0000u);
                    acc[6] += v * __uint_as_float(d3 << 16);
                    acc[7] += v * __uint_as_float(d3 & 0xFFFF0000u);
                }
            }
        }

        // reduce across the 4 edge groups (lane bits 4,5)
        #pragma unroll
        for (int j = 0; j < 8; ++j) {
            acc[j] += __shfl_xor(acc[j], 16);
            acc[j] += __shfl_xor(acc[j], 32);
        }

        if (lane < 16) {
            float* op = out + (size_t)row * D + lane * 8;
            *(float4*)(op)     = make_float4(acc[0], acc[1], acc[2], acc[3]);
            *(float4*)(op + 4) = make_float4(acc[4], acc[5], acc[6], acc[7]);
        }
    }
}

// ---------------------------------------------------------------------------
// Fallback (ws too small): atomic scatter
// ---------------------------------------------------------------------------
__global__ __launch_bounds__(256) void scatter_edges(
    const int* __restrict__ er, const int* __restrict__ ec,
    const float* __restrict__ ev, const __hip_bfloat16* __restrict__ h,
    float* __restrict__ out, int n_edges)
{
    int gw   = (blockIdx.x * 256 + threadIdx.x) >> 6;
    int lane = threadIdx.x & 63;
    if (gw >= n_edges) return;
    int r = er[gw];
    int c = ec[gw];
    float v = ev[gw];
    unsigned hv = *(const unsigned*)(h + (size_t)c * D + lane * 2);
    float* op = out + (size_t)r * D + lane * 2;
    atomicAdd(op,     v * __uint_as_float(hv << 16));
    atomicAdd(op + 1, v * __uint_as_float(hv & 0xFFFF0000u));
}

extern "C" void kernel_launch(void* const* d_in, const int* in_sizes, int n_in,
                              void* d_out, int out_size, void* d_ws, size_t ws_size,
                              hipStream_t stream) {
    const float* x  = (const float*)d_in[0];
    const int*   er = (const int*)d_in[1];
    const int*   ec = (const int*)d_in[2];
    const float* ev = (const float*)d_in[3];
    const float* W  = (const float*)d_in[4];
    const float* Wg = (const float*)d_in[5];
    const float* bg = (const float*)d_in[6];
    float* out = (float*)d_out;

    const int n_nodes = in_sizes[0] / D;
    const int n_edges = in_sizes[1];
    const int nbkt = (n_nodes + 127) >> 7;   // 128-row buckets
    const int gemm_blocks = (n_nodes + BM - 1) / BM;
    const int bin_blocks  = (n_edges + CHUNK - 1) / CHUNK;

    char* ws = (char*)d_ws;
    size_t off = 0;
    auto alloc = [&](size_t bytes) {
        char* p = ws + off;
        off += (bytes + 15) & ~size_t(15);
        return p;
    };
    __hip_bfloat16* h = (__hip_bfloat16*)alloc((size_t)n_nodes * D * sizeof(__hip_bfloat16));
    unsigned short* wt_sw = (unsigned short*)alloc((size_t)D * D * sizeof(unsigned short));
    uint2* bucketArr = (uint2*)alloc((size_t)nbkt * BKT_STRIDE * sizeof(uint2));
    int*   gcursor   = (int*)  alloc(NBKT_PAD * sizeof(int));   // | contiguous
    int*   ovfCur    = (int*)  alloc(16);                       // | memset
    uint4* ovfArr    = (uint4*)alloc((size_t)OVF_CAP * sizeof(uint4));
    bool have_ws = off <= ws_size;

    // W -> transposed, pre-swizzled bf16
    transpose_W<<<D * D / 256, 256, 0, stream>>>(W, wt_sw);

    if (have_ws) {
        hipMemsetAsync(gcursor, 0, NBKT_PAD * sizeof(int) + 16, stream);  // gcursor+ovfCur
        // fused bin (first) + GEMM: co-scheduled from dispatch 0
        gemm_bin<<<bin_blocks + gemm_blocks, 256, 0, stream>>>(
            x, wt_sw, Wg, bg, h, er, ec, ev, gcursor, bucketArr, ovfCur, ovfArr,
            n_nodes, n_edges, bin_blocks);
        sort_gather<<<nbkt, 256, 0, stream>>>(gcursor, bucketArr, ovfCur, ovfArr, h, out, n_nodes);
    } else {
        // fallback: gemm only (bin_blocks = 0), then atomic scatter
        gemm_bin<<<gemm_blocks, 256, 0, stream>>>(
            x, wt_sw, Wg, bg, h, er, ec, ev, (int*)nullptr, (uint2*)nullptr,
            (int*)nullptr, (uint4*)nullptr, n_nodes, n_edges, 0);
        hipMemsetAsync(d_out, 0, (size_t)out_size * sizeof(float), stream);
        int blocks = (n_edges + 3) / 4;
        scatter_edges<<<blocks, 256, 0, stream>>>(er, ec, ev, h, out, n_edges);
    }
}